// Round 15
// baseline (907.509 us; speedup 1.0000x reference)
//
#include <hip/hip_runtime.h>

typedef __attribute__((ext_vector_type(4))) float f32x4;
typedef __attribute__((ext_vector_type(16))) float f32x16;
typedef __attribute__((ext_vector_type(8))) short short8;

#define DEVI static __device__ __forceinline__

DEVI unsigned short f2bf(float f) {
  unsigned int u = __float_as_uint(f);
  u += 0x7FFFu + ((u >> 16) & 1u);
  return (unsigned short)(u >> 16);
}
DEVI float bf2f(unsigned short s) { return __uint_as_float(((unsigned int)s) << 16); }
DEVI unsigned int pack2(float lo, float hi) {
  return ((unsigned int)f2bf(hi) << 16) | (unsigned int)f2bf(lo);
}

#define GL2LDS(gp, lp)                                                        \
  __builtin_amdgcn_global_load_lds(                                           \
      (const __attribute__((address_space(1))) void*)(const void*)(gp),       \
      (__attribute__((address_space(3))) void*)(void*)(lp), 16, 0, 0)

#define BARRIER __builtin_amdgcn_s_barrier()
#define LGKM0                                                                 \
  do {                                                                        \
    asm volatile("s_waitcnt lgkmcnt(0)" ::: "memory");                        \
    __builtin_amdgcn_sched_barrier(0);                                        \
  } while (0)

// ---------------- f32 -> bf16 convert ----------------
__global__ __launch_bounds__(256) void k_cvt_bf16(const float* __restrict__ src,
                                                  unsigned short* __restrict__ dst, int n4) {
  int i = blockIdx.x * 256 + threadIdx.x;
  if (i < n4) {
    float4 v = ((const float4*)src)[i];
    uint2 o; o.x = pack2(v.x, v.y); o.y = pack2(v.z, v.w);
    ((uint2*)dst)[i] = o;
  }
}

// ---------------- 128x128 pipelined GEMM: C = A * B^T (bf16) ----------------
// (R5/R12-proven verbatim.)
template <bool RES>
__global__ __launch_bounds__(256) void k_gemm_bt(const unsigned short* __restrict__ A,
                                                 const unsigned short* __restrict__ B,
                                                 unsigned short* __restrict__ C,
                                                 const float* __restrict__ resid, int N) {
  constexpr int K = 2048;
  __shared__ unsigned short lA[2][128 * 64];
  __shared__ unsigned short lB[2][128 * 64];
  const int tid = threadIdx.x;
  const int lane = tid & 63;
  const int wave = tid >> 6;
  const int wr = wave >> 1, wc = wave & 1;
  const int nx = gridDim.x;
  const int lin = blockIdx.y * nx + blockIdx.x;
  const int cpx = (nx * gridDim.y) >> 3;
  const int swz = (lin & 7) * cpx + (lin >> 3);
  const long mBase = (long)(swz / nx) * 128;
  const long nBase = (long)(swz % nx) * 128;

  f32x4 acc[4][4] = {};

  auto stage = [&](int buf, int k0) {
#pragma unroll
    for (int it = 0; it < 4; it++) {
      int idx = it * 256 + tid;
      int row = idx >> 3, kc = idx & 7;
      int skc = kc ^ (row & 7);
      int lbase = (it * 256 + (tid & ~63)) * 8;
      GL2LDS(A + (mBase + row) * (long)K + k0 + skc * 8, &lA[buf][lbase]);
      GL2LDS(B + (nBase + row) * (long)K + k0 + skc * 8, &lB[buf][lbase]);
    }
  };

  stage(0, 0);
  for (int t = 0; t < 32; t++) {
    const int cur = t & 1;
    if (t < 31) {
      stage(cur ^ 1, (t + 1) * 64);
      asm volatile("s_waitcnt vmcnt(8)" ::: "memory");
    } else {
      asm volatile("s_waitcnt vmcnt(0)" ::: "memory");
    }
    __builtin_amdgcn_s_barrier();
    __builtin_amdgcn_sched_barrier(0);
    const unsigned short* bA = &lA[cur][0];
    const unsigned short* bB = &lB[cur][0];
#pragma unroll
    for (int kb = 0; kb < 2; kb++) {
      short8 af[4], bfr[4];
#pragma unroll
      for (int mt = 0; mt < 4; mt++) {
        int row = wr * 64 + mt * 16 + (lane & 15);
        int slot = (kb * 4 + (lane >> 4)) ^ (row & 7);
        af[mt] = *(const short8*)&bA[row * 64 + slot * 8];
      }
#pragma unroll
      for (int nt = 0; nt < 4; nt++) {
        int row = wc * 64 + nt * 16 + (lane & 15);
        int slot = (kb * 4 + (lane >> 4)) ^ (row & 7);
        bfr[nt] = *(const short8*)&bB[row * 64 + slot * 8];
      }
#pragma unroll
      for (int mt = 0; mt < 4; mt++)
#pragma unroll
        for (int nt = 0; nt < 4; nt++)
          acc[mt][nt] = __builtin_amdgcn_mfma_f32_16x16x32_bf16(af[mt], bfr[nt], acc[mt][nt], 0, 0, 0);
    }
    __builtin_amdgcn_sched_barrier(0);
    __builtin_amdgcn_s_barrier();
  }
#pragma unroll
  for (int mt = 0; mt < 4; mt++) {
#pragma unroll
    for (int nt = 0; nt < 4; nt++) {
#pragma unroll
      for (int j = 0; j < 4; j++) {
        long row = mBase + wr * 64 + mt * 16 + (lane >> 4) * 4 + j;
        long col = nBase + wc * 64 + nt * 16 + (lane & 15);
        float v = acc[mt][nt][j];
        if constexpr (RES) v = resid[row * (long)N + col] + fmaxf(v, 0.0f);
        C[row * (long)N + col] = f2bf(v);
      }
    }
  }
}

// ---------------- 256x256 8-phase GEMM, 32x32x16 MFMA -----------------------
// Identical staging / barriers / vmcnt schedule to the R5-proven template.
// Only the fragment reads, MFMA shape, and epilogue index mapping change.
// A-frag: row=lane&31, k0=(lane>>5)*8 per K=16 step; C/D: col=lane&31,
// row=(reg&3)+8*(reg>>2)+4*(lane>>5)  [guide §3, m74/m101-verified].
template <bool RES>
__global__ __launch_bounds__(512, 1) void k_gemm256_8p(const unsigned short* __restrict__ A,
                                                       const unsigned short* __restrict__ B,
                                                       unsigned short* __restrict__ C,
                                                       const unsigned short* __restrict__ residb,
                                                       int N) {
  constexpr int K = 2048;
  __shared__ unsigned short lA[2][2][128 * 64];
  __shared__ unsigned short lB[2][2][128 * 64];
  const int tid = threadIdx.x;
  const int lane = tid & 63;
  const int wave = tid >> 6;
  const int wr = wave >> 2, wc = wave & 3;  // wave tile 128(M) x 64(N)
  const int lin = blockIdx.y * 8 + blockIdx.x;
  const int swz = (lin & 7) * 160 + (lin >> 3);
  const long mBase = (long)(swz >> 3) * 256;
  const long nBase = (long)(swz & 7) * 256;

  f32x16 acc[4][2] = {};   // 4 m-tiles(32) x 2 n-tiles(32)
  short8 afr[2][4];        // current m-half: 2 m-tiles x 4 k-steps
  short8 b0[4], b1[4];     // n-tile 0 / 1, 4 k-steps each

  auto stageA = [&](int buf, int half, int t) {
    const unsigned short* base = A + (mBase + half * 128) * (long)K + (long)t * 64;
    unsigned short* lds = &lA[buf][half][0];
#pragma unroll
    for (int it = 0; it < 2; it++) {
      int r = it * 64 + (tid >> 3);
      int kc = tid & 7;
      int skc = kc ^ (r & 7);
      GL2LDS(base + (long)r * K + skc * 8, lds + (it * 512 + (tid & ~63)) * 8);
    }
  };
  auto stageB = [&](int buf, int half, int t) {
    const unsigned short* base = B + (nBase + half * 128) * (long)K + (long)t * 64;
    unsigned short* lds = &lB[buf][half][0];
#pragma unroll
    for (int it = 0; it < 2; it++) {
      int r = it * 64 + (tid >> 3);
      int kc = tid & 7;
      int skc = kc ^ (r & 7);
      GL2LDS(base + (long)r * K + skc * 8, lds + (it * 512 + (tid & ~63)) * 8);
    }
  };
  auto readA = [&](int buf, int mh) {  // 8 x ds_read_b128
#pragma unroll
    for (int mtl = 0; mtl < 2; mtl++)
#pragma unroll
      for (int ks = 0; ks < 4; ks++) {
        int r = mh * 64 + mtl * 32 + (lane & 31);
        int slot = (ks * 2 + (lane >> 5)) ^ (r & 7);
        afr[mtl][ks] = *(const short8*)&lA[buf][wr][r * 64 + slot * 8];
      }
  };
  auto readB0 = [&](int buf) {  // 4 x ds_read_b128 (n-tile 0)
#pragma unroll
    for (int ks = 0; ks < 4; ks++) {
      int col = wc * 64 + (lane & 31);
      int half = col >> 7, r = col & 127;
      int slot = (ks * 2 + (lane >> 5)) ^ (r & 7);
      b0[ks] = *(const short8*)&lB[buf][half][r * 64 + slot * 8];
    }
  };
  auto readB1 = [&](int buf) {  // 4 x ds_read_b128 (n-tile 1)
#pragma unroll
    for (int ks = 0; ks < 4; ks++) {
      int col = wc * 64 + 32 + (lane & 31);
      int half = col >> 7, r = col & 127;
      int slot = (ks * 2 + (lane >> 5)) ^ (r & 7);
      b1[ks] = *(const short8*)&lB[buf][half][r * 64 + slot * 8];
    }
  };
  auto mfmaQ0 = [&](int mh) {  // 8 MFMA vs b0 (n-tile 0)
    __builtin_amdgcn_s_setprio(1);
#pragma unroll
    for (int ks = 0; ks < 4; ks++)
#pragma unroll
      for (int mtl = 0; mtl < 2; mtl++)
        acc[mh * 2 + mtl][0] = __builtin_amdgcn_mfma_f32_32x32x16_bf16(
            afr[mtl][ks], b0[ks], acc[mh * 2 + mtl][0], 0, 0, 0);
    __builtin_amdgcn_s_setprio(0);
  };
  auto mfmaQ1 = [&](int mh) {  // 8 MFMA vs b1 (n-tile 1)
    __builtin_amdgcn_s_setprio(1);
#pragma unroll
    for (int ks = 0; ks < 4; ks++)
#pragma unroll
      for (int mtl = 0; mtl < 2; mtl++)
        acc[mh * 2 + mtl][1] = __builtin_amdgcn_mfma_f32_32x32x16_bf16(
            afr[mtl][ks], b1[ks], acc[mh * 2 + mtl][1], 0, 0, 0);
    __builtin_amdgcn_s_setprio(0);
  };

  // prologue: tiles 0 and 1 fully staged (16 loads); wait tile 0 (oldest 8)
  stageA(0, 0, 0); stageA(0, 1, 0); stageB(0, 0, 0); stageB(0, 1, 0);
  stageA(1, 0, 1); stageA(1, 1, 1); stageB(1, 0, 1); stageB(1, 1, 1);
  asm volatile("s_waitcnt vmcnt(8)" ::: "memory");
  BARRIER;

  for (int t = 0; t < 32; t++) {
    const int cur = t & 1;
    // ---- ph0: read A-half0 + B n-tile0; stage A1(t+1)
    readA(cur, 0);
    readB0(cur);
    if (t >= 1 && t <= 30) stageA(cur ^ 1, 1, t + 1);
    BARRIER; LGKM0;
    mfmaQ0(0);
    BARRIER;
    // ---- ph1: read B n-tile1
    readB1(cur);
    BARRIER; LGKM0;
    mfmaQ1(0);
    BARRIER;
    // ---- ph2: read A-half1; stage B0(t+2)
    readA(cur, 1);
    if (t <= 29) stageB(cur, 0, t + 2);
    BARRIER; LGKM0;
    mfmaQ0(1);
    BARRIER;
    // ---- ph3: stage B1(t+2), A0(t+2); MFMA; counted vmcnt (never 0 mid-loop)
    if (t <= 29) { stageB(cur, 1, t + 2); stageA(cur, 0, t + 2); }
    mfmaQ1(1);
    if (t <= 29) {
      asm volatile("s_waitcnt vmcnt(6)" ::: "memory");
    } else if (t == 30) {
      asm volatile("s_waitcnt vmcnt(0)" ::: "memory");
    }
    BARRIER;
  }

  // epilogue: C = bf16(resid_bf16 + relu(acc)); 32x32 C/D mapping
#pragma unroll
  for (int mt = 0; mt < 4; mt++) {
#pragma unroll
    for (int nt = 0; nt < 2; nt++) {
#pragma unroll
      for (int reg = 0; reg < 16; reg++) {
        long row = mBase + wr * 128 + mt * 32 + (reg & 3) + 8 * (reg >> 2) + 4 * (lane >> 5);
        long col = nBase + wc * 64 + nt * 32 + (lane & 31);
        float v = acc[mt][nt][reg];
        if constexpr (RES) v = bf2f(residb[row * (long)N + col]) + fmaxf(v, 0.0f);
        C[row * (long)N + col] = f2bf(v);
      }
    }
  }
}

// ---------------- per-group inner attention, reg-prefetch phase 2 -----------
__global__ __launch_bounds__(256) void k_attn_inner(const unsigned short* __restrict__ fe,
                                                    const unsigned short* __restrict__ topkb,
                                                    unsigned short* __restrict__ agg) {
  __shared__ unsigned short attb[128 * 136];
  __shared__ unsigned short featT[64 * 128];
  __shared__ float redmax[2 * 128];
  __shared__ float redsum[2 * 128];
  const int tid = threadIdx.x;
  const int lane = tid & 63;
  const int wave = tid >> 6;
  const int wr = wave >> 1, wc = wave & 1;
  const int g = blockIdx.x;
  const unsigned short* feG = fe + (long)g * 128 * 256;

  f32x4 s[4][4] = {};
#pragma unroll
  for (int kb = 0; kb < 8; kb++) {
    short8 af[4], bfr[4];
#pragma unroll
    for (int mt = 0; mt < 4; mt++) {
      int row = wr * 64 + mt * 16 + (lane & 15);
      af[mt] = *(const short8*)(feG + row * 256 + kb * 32 + (lane >> 4) * 8);
    }
#pragma unroll
    for (int nt = 0; nt < 4; nt++) {
      int row = wc * 64 + nt * 16 + (lane & 15);
      bfr[nt] = *(const short8*)(feG + row * 256 + kb * 32 + (lane >> 4) * 8);
    }
#pragma unroll
    for (int mt = 0; mt < 4; mt++)
#pragma unroll
      for (int nt = 0; nt < 4; nt++)
        s[mt][nt] = __builtin_amdgcn_mfma_f32_16x16x32_bf16(af[mt], bfr[nt], s[mt][nt], 0, 0, 0);
  }

  const float cexp = 0.0625f * 1.44269504088896f;
#pragma unroll
  for (int mt = 0; mt < 4; mt++) {
#pragma unroll
    for (int j = 0; j < 4; j++) {
      float m = fmaxf(fmaxf(s[mt][0][j], s[mt][1][j]), fmaxf(s[mt][2][j], s[mt][3][j]));
#pragma unroll
      for (int d = 1; d < 16; d <<= 1) m = fmaxf(m, __shfl_xor(m, d, 64));
      int r = wr * 64 + mt * 16 + (lane >> 4) * 4 + j;
      if ((lane & 15) == 0) redmax[wc * 128 + r] = m;
    }
  }
  __syncthreads();
#pragma unroll
  for (int mt = 0; mt < 4; mt++) {
#pragma unroll
    for (int j = 0; j < 4; j++) {
      int r = wr * 64 + mt * 16 + (lane >> 4) * 4 + j;
      float M = fmaxf(redmax[r], redmax[128 + r]);
      float sm = 0.f;
#pragma unroll
      for (int nt = 0; nt < 4; nt++) {
        float p = exp2f((s[mt][nt][j] - M) * cexp);
        s[mt][nt][j] = p;
        sm += p;
      }
#pragma unroll
      for (int d = 1; d < 16; d <<= 1) sm += __shfl_xor(sm, d, 64);
      if ((lane & 15) == 0) redsum[wc * 128 + r] = sm;
    }
  }
  __syncthreads();
#pragma unroll
  for (int mt = 0; mt < 4; mt++) {
#pragma unroll
    for (int j = 0; j < 4; j++) {
      int r = wr * 64 + mt * 16 + (lane >> 4) * 4 + j;
      float inv = 1.0f / (redsum[r] + redsum[128 + r]);
#pragma unroll
      for (int nt = 0; nt < 4; nt++) {
        int c = wc * 64 + nt * 16 + (lane & 15);
        attb[r * 136 + c] = f2bf(s[mt][nt][j] * inv);
      }
    }
  }

  // ---- Phase 2: agg = att @ feat, register-prefetch double buffer ----
  const int pl = tid >> 3;
  const int pkc = tid & 7;
  auto loadChunk = [&](uint4 (&r)[4], int ch) {
#pragma unroll
    for (int i = 0; i < 4; i++) {
      int l = i * 32 + pl;
      r[i] = *(const uint4*)(topkb + ((long)g * 128 + l) * 2048 + ch * 64 + pkc * 8);
    }
  };
  auto writeChunk = [&](const uint4 (&r)[4]) {
#pragma unroll
    for (int i = 0; i < 4; i++) {
      int l = i * 32 + pl;
      unsigned short v[8];
      v[0] = (unsigned short)(r[i].x & 0xffff); v[1] = (unsigned short)(r[i].x >> 16);
      v[2] = (unsigned short)(r[i].y & 0xffff); v[3] = (unsigned short)(r[i].y >> 16);
      v[4] = (unsigned short)(r[i].z & 0xffff); v[5] = (unsigned short)(r[i].z >> 16);
      v[6] = (unsigned short)(r[i].w & 0xffff); v[7] = (unsigned short)(r[i].w >> 16);
      int lx = l ^ (pkc << 3);
#pragma unroll
      for (int j = 0; j < 8; j++) featT[(pkc * 8 + j) * 128 + lx] = v[j];
    }
  };
  auto computeChunk = [&](int ch) {
    f32x4 c[2][4] = {};
#pragma unroll
    for (int kb = 0; kb < 4; kb++) {
      short8 af2[2], bf2v[4];
#pragma unroll
      for (int mt = 0; mt < 2; mt++) {
        int r = wave * 32 + mt * 16 + (lane & 15);
        af2[mt] = *(const short8*)&attb[r * 136 + kb * 32 + (lane >> 4) * 8];
      }
#pragma unroll
      for (int nt = 0; nt < 4; nt++) {
        int cc = nt * 16 + (lane & 15);
        int l0 = (kb * 32 + (lane >> 4) * 8) ^ (((cc >> 3) & 7) << 3);
        bf2v[nt] = *(const short8*)&featT[cc * 128 + l0];
      }
#pragma unroll
      for (int mt = 0; mt < 2; mt++)
#pragma unroll
        for (int nt = 0; nt < 4; nt++)
          c[mt][nt] = __builtin_amdgcn_mfma_f32_16x16x32_bf16(af2[mt], bf2v[nt], c[mt][nt], 0, 0, 0);
    }
#pragma unroll
    for (int mt = 0; mt < 2; mt++)
#pragma unroll
      for (int nt = 0; nt < 4; nt++)
#pragma unroll
        for (int j = 0; j < 4; j++) {
          long row = (long)g * 128 + wave * 32 + mt * 16 + (lane >> 4) * 4 + j;
          int col = ch * 64 + nt * 16 + (lane & 15);
          agg[row * 2048 + col] = f2bf(c[mt][nt][j]);
        }
  };

  uint4 rA[4], rB[4];
  loadChunk(rA, 0);
  for (int ch = 0; ch < 32; ch += 2) {
    __syncthreads();
    writeChunk(rA);
    loadChunk(rB, ch + 1);
    __syncthreads();
    computeChunk(ch);
    __syncthreads();
    writeChunk(rB);
    if (ch + 2 < 32) loadChunk(rA, ch + 2);
    __syncthreads();
    computeChunk(ch + 1);
  }
}

// ---------------- pe = protos @ wi2^T  [20,5,256] ---------------------------
__global__ __launch_bounds__(256) void k_pe(const float* __restrict__ protos,
                                            const float* __restrict__ wi2,
                                            float* __restrict__ pe) {
  int n = blockIdx.x, oc = blockIdx.y, tid = threadIdx.x;
  if (tid < 160) {
    int p = tid >> 5, o = oc * 32 + (tid & 31);
    const float* pr = protos + ((long)n * 5 + p) * 2048;
    const float* wr = wi2 + (long)o * 2048;
    float acc = 0.f;
    for (int cidx = 0; cidx < 2048; cidx += 4) {
      float4 a = *(const float4*)(pr + cidx);
      float4 b = *(const float4*)(wr + cidx);
      acc += a.x * b.x + a.y * b.y + a.z * b.z + a.w * b.w;
    }
    pe[((long)n * 5 + p) * 256 + o] = acc;
  }
}

// ---------------- q[n,p,c] = sum_o pe[n,p,o] * wi1[o,c]  (f32) --------------
__global__ __launch_bounds__(256) void k_q(const float* __restrict__ pe,
                                           const float* __restrict__ wi1,
                                           float* __restrict__ q) {
  __shared__ float pel[1280];
  int n = blockIdx.x, cb = blockIdx.y, tid = threadIdx.x;
  for (int i = tid; i < 1280; i += 256) pel[i] = pe[(long)n * 1280 + i];
  __syncthreads();
  int c = cb * 256 + tid;
  float a[5] = {0.f, 0.f, 0.f, 0.f, 0.f};
  for (int o = 0; o < 256; o++) {
    float w = wi1[(long)o * 2048 + c];
#pragma unroll
    for (int p = 0; p < 5; p++) a[p] += pel[p * 256 + o] * w;
  }
#pragma unroll
  for (int p = 0; p < 5; p++) q[((long)n * 5 + p) * 2048 + c] = a[p];
}

// ------- lg partial: lgp[cb][n,p,m] (R5 2-chunk) ---------------------------
__global__ __launch_bounds__(256) void k_lg(const float* __restrict__ q,
                                            const unsigned short* __restrict__ feats,
                                            float* __restrict__ lgp) {
  __shared__ float ql[5 * 1024];
  int n = blockIdx.x, mc = blockIdx.y, cb = blockIdx.z, tid = threadIdx.x;
  const float4* qs = (const float4*)(q + (long)n * 5 * 2048);
  for (int i = tid; i < 1280; i += 256) {
    int p = i >> 8, r = i & 255;
    ((float4*)ql)[i] = qs[p * 512 + cb * 256 + r];
  }
  __syncthreads();
  int m = mc * 256 + tid;
  const unsigned short* fr = feats + ((long)n * 2048 + m) * 2048 + cb * 1024;
  float a[5] = {0.f, 0.f, 0.f, 0.f, 0.f};
  for (int c = 0; c < 1024; c += 8) {
    uint4 w = *(const uint4*)(fr + c);
    float f[8];
    f[0] = bf2f((unsigned short)(w.x & 0xffff)); f[1] = bf2f((unsigned short)(w.x >> 16));
    f[2] = bf2f((unsigned short)(w.y & 0xffff)); f[3] = bf2f((unsigned short)(w.y >> 16));
    f[4] = bf2f((unsigned short)(w.z & 0xffff)); f[5] = bf2f((unsigned short)(w.z >> 16));
    f[6] = bf2f((unsigned short)(w.w & 0xffff)); f[7] = bf2f((unsigned short)(w.w >> 16));
#pragma unroll
    for (int j = 0; j < 8; j++) {
      float fv = f[j];
#pragma unroll
      for (int p = 0; p < 5; p++) a[p] += fv * ql[p * 1024 + c + j];
    }
  }
#pragma unroll
  for (int p = 0; p < 5; p++)
    lgp[((long)cb * 100 + n * 5 + p) * 2048 + m] = a[p] * 0.0625f;
}

// ---------------- softmax over m (2048) per (n,p), 2 partials ---------------
__global__ __launch_bounds__(256) void k_sm(const float* __restrict__ lgp,
                                            float* __restrict__ att2) {
  __shared__ float red[4], red2[4];
  int b = blockIdx.x, tid = threadIdx.x;
  const float* s0 = lgp + (long)b * 2048;
  const float* s1 = lgp + (long)100 * 2048 + (long)b * 2048;
  float v[8];
  float mx = -1e30f;
#pragma unroll
  for (int i = 0; i < 8; i++) {
    v[i] = s0[i * 256 + tid] + s1[i * 256 + tid];
    mx = fmaxf(mx, v[i]);
  }
#pragma unroll
  for (int d = 1; d < 64; d <<= 1) mx = fmaxf(mx, __shfl_xor(mx, d, 64));
  if ((tid & 63) == 0) red[tid >> 6] = mx;
  __syncthreads();
  mx = fmaxf(fmaxf(red[0], red[1]), fmaxf(red[2], red[3]));
  float sm = 0.f;
#pragma unroll
  for (int i = 0; i < 8; i++) { v[i] = exp2f((v[i] - mx) * 1.44269504088896f); sm += v[i]; }
#pragma unroll
  for (int d = 1; d < 64; d <<= 1) sm += __shfl_xor(sm, d, 64);
  if ((tid & 63) == 0) red2[tid >> 6] = sm;
  __syncthreads();
  float inv = 1.0f / (red2[0] + red2[1] + red2[2] + red2[3]);
  float* dst = att2 + (long)b * 2048;
#pragma unroll
  for (int i = 0; i < 8; i++) dst[i * 256 + tid] = v[i] * inv;
}

// ---------------- un_protos partials: att2 @ fa (8 m-chunks, 8B loads) ------
__global__ __launch_bounds__(256) void k_out_part(const float* __restrict__ att2,
                                                  const unsigned short* __restrict__ feats,
                                                  float* __restrict__ partial) {
  __shared__ float a2[5 * 256];
  int n = blockIdx.x, cb = blockIdx.y, ms = blockIdx.z;
  int tid = threadIdx.x;
  const float* src = att2 + (long)n * 5 * 2048 + ms * 256;
  for (int i = tid; i < 320; i += 256) {
    int p = i >> 6, r = i & 63;
    ((float4*)a2)[i] = *(const float4*)(src + p * 2048 + r * 4);
  }
  __syncthreads();
  int c0 = cb * 1024 + tid * 4;
  const unsigned short* fp = feats + ((long)n * 2048 + ms * 256) * 2048 + c0;
  float acc[5][4] = {};
  for (int m = 0; m < 256; m++) {
    uint2 w = *(const uint2*)(fp + (long)m * 2048);
    float f0 = bf2f((unsigned short)(w.x & 0xffff));
    float f1 = bf2f((unsigned short)(w.x >> 16));
    float f2 = bf2f((unsigned short)(w.y & 0xffff));
    float f3 = bf2f((unsigned short)(w.y >> 16));
#pragma unroll
    for (int p = 0; p < 5; p++) {
      float a = a2[p * 256 + m];
      acc[p][0] += a * f0; acc[p][1] += a * f1; acc[p][2] += a * f2; acc[p][3] += a * f3;
    }
  }
  float* pp = partial + ((long)ms * 100 + (long)n * 5) * 2048;
#pragma unroll
  for (int p = 0; p < 5; p++) {
    float4 o; o.x = acc[p][0]; o.y = acc[p][1]; o.z = acc[p][2]; o.w = acc[p][3];
    *(float4*)(pp + p * 2048 + c0) = o;
  }
}

__global__ __launch_bounds__(256) void k_out_red(const float* __restrict__ partial,
                                                 float* __restrict__ outp) {
  int i = blockIdx.x * 256 + threadIdx.x;  // f32x4 idx < 51200
  const f32x4* P = (const f32x4*)partial;
  f32x4 s = P[i];
#pragma unroll
  for (int j = 1; j < 8; j++) s += P[(long)j * 51200 + i];
  ((f32x4*)outp)[i] = s;
}

extern "C" void kernel_launch(void* const* d_in, const int* in_sizes, int n_in,
                              void* d_out, int out_size, void* d_ws, size_t ws_size,
                              hipStream_t stream) {
  const float* topk = (const float*)d_in[0];
  const float* protos = (const float*)d_in[1];
  const float* w1 = (const float*)d_in[2];
  const float* wt = (const float*)d_in[3];
  const float* wi1 = (const float*)d_in[4];
  const float* wi2 = (const float*)d_in[5];
  float* outp = (float*)d_out;

  char* ws = (char*)d_ws;
  size_t off = 0;
  auto alloc = [&](size_t bytes) -> void* {
    void* p = ws + off;
    off += (bytes + 255) & ~(size_t)255;
    return p;
  };
  unsigned short* w1b = (unsigned short*)alloc((size_t)256 * 2048 * 2);
  unsigned short* wtb = (unsigned short*)alloc((size_t)2048 * 2048 * 2);
  unsigned short* topkb = (unsigned short*)alloc((size_t)40960 * 2048 * 2);  // aliased by feats
  unsigned short* fe = (unsigned short*)alloc((size_t)40960 * 256 * 2);
  unsigned short* agg = (unsigned short*)alloc((size_t)40960 * 2048 * 2);
  float* pe = (float*)alloc((size_t)20 * 5 * 256 * 4);
  float* q = (float*)alloc((size_t)20 * 5 * 2048 * 4);
  float* lgp = (float*)alloc((size_t)2 * 100 * 2048 * 4);
  float* att2 = (float*)alloc((size_t)20 * 5 * 2048 * 4);
  float* partial = (float*)alloc((size_t)8 * 100 * 2048 * 4);
  unsigned short* feats = topkb;  // topkb dead after attn

  k_cvt_bf16<<<512, 256, 0, stream>>>(w1, w1b, 131072);
  k_cvt_bf16<<<4096, 256, 0, stream>>>(wt, wtb, 1048576);
  k_cvt_bf16<<<81920, 256, 0, stream>>>(topk, topkb, 20971520);

  // fe = topkb @ W1^T
  k_gemm_bt<false><<<dim3(2, 320), 256, 0, stream>>>(topkb, w1b, fe, nullptr, 256);
  // inner attention -> agg  (register-prefetch phase 2)
  k_attn_inner<<<320, 256, 0, stream>>>(fe, topkb, agg);
  // feats = topkb + relu(agg @ Wt^T)   (8-phase, 32x32x16 MFMA)
  k_gemm256_8p<true><<<dim3(8, 160), 512, 0, stream>>>(agg, wtb, feats, topkb, 2048);
  // inter attention (fae eliminated: q = pe @ wi1)
  k_pe<<<dim3(20, 8), 256, 0, stream>>>(protos, wi2, pe);
  k_q<<<dim3(20, 8), 256, 0, stream>>>(pe, wi1, q);
  k_lg<<<dim3(20, 8, 2), 256, 0, stream>>>(q, feats, lgp);
  k_sm<<<100, 256, 0, stream>>>(lgp, att2);
  // output
  k_out_part<<<dim3(20, 2, 8), 256, 0, stream>>>(att2, feats, partial);
  k_out_red<<<200, 256, 0, stream>>>(partial, outp);
}

// Round 16
// 893.272 us; speedup vs baseline: 1.0159x; 1.0159x over previous
//
#include <hip/hip_runtime.h>

typedef __attribute__((ext_vector_type(4))) float f32x4;
typedef __attribute__((ext_vector_type(8))) short short8;

#define DEVI static __device__ __forceinline__

DEVI unsigned short f2bf(float f) {
  unsigned int u = __float_as_uint(f);
  u += 0x7FFFu + ((u >> 16) & 1u);
  return (unsigned short)(u >> 16);
}
DEVI float bf2f(unsigned short s) { return __uint_as_float(((unsigned int)s) << 16); }
DEVI unsigned int pack2(float lo, float hi) {
  return ((unsigned int)f2bf(hi) << 16) | (unsigned int)f2bf(lo);
}

#define GL2LDS(gp, lp)                                                        \
  __builtin_amdgcn_global_load_lds(                                           \
      (const __attribute__((address_space(1))) void*)(const void*)(gp),       \
      (__attribute__((address_space(3))) void*)(void*)(lp), 16, 0, 0)

#define BARRIER __builtin_amdgcn_s_barrier()
#define LGKM0                                                                 \
  do {                                                                        \
    asm volatile("s_waitcnt lgkmcnt(0)" ::: "memory");                        \
    __builtin_amdgcn_sched_barrier(0);                                        \
  } while (0)

// ---------------- f32 -> bf16 convert ----------------
__global__ __launch_bounds__(256) void k_cvt_bf16(const float* __restrict__ src,
                                                  unsigned short* __restrict__ dst, int n4) {
  int i = blockIdx.x * 256 + threadIdx.x;
  if (i < n4) {
    float4 v = ((const float4*)src)[i];
    uint2 o; o.x = pack2(v.x, v.y); o.y = pack2(v.z, v.w);
    ((uint2*)dst)[i] = o;
  }
}

// ---------------- 128x128 pipelined GEMM: C = A * B^T (bf16) ----------------
// (R5/R12-proven verbatim.)
template <bool RES>
__global__ __launch_bounds__(256) void k_gemm_bt(const unsigned short* __restrict__ A,
                                                 const unsigned short* __restrict__ B,
                                                 unsigned short* __restrict__ C,
                                                 const float* __restrict__ resid, int N) {
  constexpr int K = 2048;
  __shared__ unsigned short lA[2][128 * 64];
  __shared__ unsigned short lB[2][128 * 64];
  const int tid = threadIdx.x;
  const int lane = tid & 63;
  const int wave = tid >> 6;
  const int wr = wave >> 1, wc = wave & 1;
  const int nx = gridDim.x;
  const int lin = blockIdx.y * nx + blockIdx.x;
  const int cpx = (nx * gridDim.y) >> 3;
  const int swz = (lin & 7) * cpx + (lin >> 3);
  const long mBase = (long)(swz / nx) * 128;
  const long nBase = (long)(swz % nx) * 128;

  f32x4 acc[4][4] = {};

  auto stage = [&](int buf, int k0) {
#pragma unroll
    for (int it = 0; it < 4; it++) {
      int idx = it * 256 + tid;
      int row = idx >> 3, kc = idx & 7;
      int skc = kc ^ (row & 7);
      int lbase = (it * 256 + (tid & ~63)) * 8;
      GL2LDS(A + (mBase + row) * (long)K + k0 + skc * 8, &lA[buf][lbase]);
      GL2LDS(B + (nBase + row) * (long)K + k0 + skc * 8, &lB[buf][lbase]);
    }
  };

  stage(0, 0);
  for (int t = 0; t < 32; t++) {
    const int cur = t & 1;
    if (t < 31) {
      stage(cur ^ 1, (t + 1) * 64);
      asm volatile("s_waitcnt vmcnt(8)" ::: "memory");
    } else {
      asm volatile("s_waitcnt vmcnt(0)" ::: "memory");
    }
    __builtin_amdgcn_s_barrier();
    __builtin_amdgcn_sched_barrier(0);
    const unsigned short* bA = &lA[cur][0];
    const unsigned short* bB = &lB[cur][0];
#pragma unroll
    for (int kb = 0; kb < 2; kb++) {
      short8 af[4], bfr[4];
#pragma unroll
      for (int mt = 0; mt < 4; mt++) {
        int row = wr * 64 + mt * 16 + (lane & 15);
        int slot = (kb * 4 + (lane >> 4)) ^ (row & 7);
        af[mt] = *(const short8*)&bA[row * 64 + slot * 8];
      }
#pragma unroll
      for (int nt = 0; nt < 4; nt++) {
        int row = wc * 64 + nt * 16 + (lane & 15);
        int slot = (kb * 4 + (lane >> 4)) ^ (row & 7);
        bfr[nt] = *(const short8*)&bB[row * 64 + slot * 8];
      }
#pragma unroll
      for (int mt = 0; mt < 4; mt++)
#pragma unroll
        for (int nt = 0; nt < 4; nt++)
          acc[mt][nt] = __builtin_amdgcn_mfma_f32_16x16x32_bf16(af[mt], bfr[nt], acc[mt][nt], 0, 0, 0);
    }
    __builtin_amdgcn_sched_barrier(0);
    __builtin_amdgcn_s_barrier();
  }
#pragma unroll
  for (int mt = 0; mt < 4; mt++) {
#pragma unroll
    for (int nt = 0; nt < 4; nt++) {
#pragma unroll
      for (int j = 0; j < 4; j++) {
        long row = mBase + wr * 64 + mt * 16 + (lane >> 4) * 4 + j;
        long col = nBase + wc * 64 + nt * 16 + (lane & 15);
        float v = acc[mt][nt][j];
        if constexpr (RES) v = resid[row * (long)N + col] + fmaxf(v, 0.0f);
        C[row * (long)N + col] = f2bf(v);
      }
    }
  }
}

// ---------------- 256x256 8-phase GEMM (R5-proven schedule, verbatim) -------
template <bool RES>
__global__ __launch_bounds__(512, 1) void k_gemm256_8p(const unsigned short* __restrict__ A,
                                                       const unsigned short* __restrict__ B,
                                                       unsigned short* __restrict__ C,
                                                       const unsigned short* __restrict__ residb,
                                                       int N) {
  constexpr int K = 2048;
  __shared__ unsigned short lA[2][2][128 * 64];
  __shared__ unsigned short lB[2][2][128 * 64];
  const int tid = threadIdx.x;
  const int lane = tid & 63;
  const int wave = tid >> 6;
  const int wr = wave >> 2, wc = wave & 3;  // wave tile 128(M) x 64(N)
  const int lin = blockIdx.y * 8 + blockIdx.x;
  const int swz = (lin & 7) * 160 + (lin >> 3);
  const long mBase = (long)(swz >> 3) * 256;
  const long nBase = (long)(swz & 7) * 256;

  f32x4 acc[8][4] = {};
  short8 af[4][2];
  short8 bfr[4][2];

  auto stageA = [&](int buf, int half, int t) {
    const unsigned short* base = A + (mBase + half * 128) * (long)K + (long)t * 64;
    unsigned short* lds = &lA[buf][half][0];
#pragma unroll
    for (int it = 0; it < 2; it++) {
      int r = it * 64 + (tid >> 3);
      int kc = tid & 7;
      int skc = kc ^ (r & 7);
      GL2LDS(base + (long)r * K + skc * 8, lds + (it * 512 + (tid & ~63)) * 8);
    }
  };
  auto stageB = [&](int buf, int half, int t) {
    const unsigned short* base = B + (nBase + half * 128) * (long)K + (long)t * 64;
    unsigned short* lds = &lB[buf][half][0];
#pragma unroll
    for (int it = 0; it < 2; it++) {
      int r = it * 64 + (tid >> 3);
      int kc = tid & 7;
      int skc = kc ^ (r & 7);
      GL2LDS(base + (long)r * K + skc * 8, lds + (it * 512 + (tid & ~63)) * 8);
    }
  };
  auto readA = [&](int buf, int mhalf) {
#pragma unroll
    for (int mt = 0; mt < 4; mt++)
#pragma unroll
      for (int kb = 0; kb < 2; kb++) {
        int r = mhalf * 64 + mt * 16 + (lane & 15);
        int slot = (kb * 4 + (lane >> 4)) ^ (r & 7);
        af[mt][kb] = *(const short8*)&lA[buf][wr][r * 64 + slot * 8];
      }
  };
  auto readB = [&](int buf, int nh) {
#pragma unroll
    for (int ntl = 0; ntl < 2; ntl++)
#pragma unroll
      for (int kb = 0; kb < 2; kb++) {
        int nt = nh * 2 + ntl;
        int col = wc * 64 + nt * 16 + (lane & 15);
        int half = col >> 7, r = col & 127;
        int slot = (kb * 4 + (lane >> 4)) ^ (r & 7);
        bfr[nt][kb] = *(const short8*)&lB[buf][half][r * 64 + slot * 8];
      }
  };
  auto mfmaQ = [&](int mhalf, int nh) {
    __builtin_amdgcn_s_setprio(1);
#pragma unroll
    for (int kb = 0; kb < 2; kb++)
#pragma unroll
      for (int mt = 0; mt < 4; mt++)
#pragma unroll
        for (int ntl = 0; ntl < 2; ntl++) {
          int nt = nh * 2 + ntl;
          acc[mhalf * 4 + mt][nt] = __builtin_amdgcn_mfma_f32_16x16x32_bf16(
              af[mt][kb], bfr[nt][kb], acc[mhalf * 4 + mt][nt], 0, 0, 0);
        }
    __builtin_amdgcn_s_setprio(0);
  };

  stageA(0, 0, 0); stageA(0, 1, 0); stageB(0, 0, 0); stageB(0, 1, 0);
  stageA(1, 0, 1); stageA(1, 1, 1); stageB(1, 0, 1); stageB(1, 1, 1);
  asm volatile("s_waitcnt vmcnt(8)" ::: "memory");
  BARRIER;

  for (int t = 0; t < 32; t++) {
    const int cur = t & 1;
    readA(cur, 0);
    readB(cur, 0);
    if (t >= 1 && t <= 30) stageA(cur ^ 1, 1, t + 1);
    BARRIER; LGKM0;
    mfmaQ(0, 0);
    BARRIER;
    readB(cur, 1);
    BARRIER; LGKM0;
    mfmaQ(0, 1);
    BARRIER;
    readA(cur, 1);
    if (t <= 29) stageB(cur, 0, t + 2);
    BARRIER; LGKM0;
    mfmaQ(1, 0);
    BARRIER;
    if (t <= 29) { stageB(cur, 1, t + 2); stageA(cur, 0, t + 2); }
    mfmaQ(1, 1);
    if (t <= 29) {
      asm volatile("s_waitcnt vmcnt(6)" ::: "memory");
    } else if (t == 30) {
      asm volatile("s_waitcnt vmcnt(0)" ::: "memory");
    }
    BARRIER;
  }

#pragma unroll
  for (int mt = 0; mt < 8; mt++) {
#pragma unroll
    for (int nt = 0; nt < 4; nt++) {
#pragma unroll
      for (int j = 0; j < 4; j++) {
        long row = mBase + wr * 128 + mt * 16 + (lane >> 4) * 4 + j;
        long col = nBase + wc * 64 + nt * 16 + (lane & 15);
        float v = acc[mt][nt][j];
        if constexpr (RES) v = bf2f(residb[row * (long)N + col]) + fmaxf(v, 0.0f);
        C[row * (long)N + col] = f2bf(v);
      }
    }
  }
}

// ---------------- per-group inner attention, reg-prefetch phase 2 -----------
__global__ __launch_bounds__(256) void k_attn_inner(const unsigned short* __restrict__ fe,
                                                    const unsigned short* __restrict__ topkb,
                                                    unsigned short* __restrict__ agg) {
  __shared__ unsigned short attb[128 * 136];
  __shared__ unsigned short featT[64 * 128];
  __shared__ float redmax[2 * 128];
  __shared__ float redsum[2 * 128];
  const int tid = threadIdx.x;
  const int lane = tid & 63;
  const int wave = tid >> 6;
  const int wr = wave >> 1, wc = wave & 1;
  const int g = blockIdx.x;
  const unsigned short* feG = fe + (long)g * 128 * 256;

  f32x4 s[4][4] = {};
#pragma unroll
  for (int kb = 0; kb < 8; kb++) {
    short8 af[4], bfr[4];
#pragma unroll
    for (int mt = 0; mt < 4; mt++) {
      int row = wr * 64 + mt * 16 + (lane & 15);
      af[mt] = *(const short8*)(feG + row * 256 + kb * 32 + (lane >> 4) * 8);
    }
#pragma unroll
    for (int nt = 0; nt < 4; nt++) {
      int row = wc * 64 + nt * 16 + (lane & 15);
      bfr[nt] = *(const short8*)(feG + row * 256 + kb * 32 + (lane >> 4) * 8);
    }
#pragma unroll
    for (int mt = 0; mt < 4; mt++)
#pragma unroll
      for (int nt = 0; nt < 4; nt++)
        s[mt][nt] = __builtin_amdgcn_mfma_f32_16x16x32_bf16(af[mt], bfr[nt], s[mt][nt], 0, 0, 0);
  }

  const float cexp = 0.0625f * 1.44269504088896f;
#pragma unroll
  for (int mt = 0; mt < 4; mt++) {
#pragma unroll
    for (int j = 0; j < 4; j++) {
      float m = fmaxf(fmaxf(s[mt][0][j], s[mt][1][j]), fmaxf(s[mt][2][j], s[mt][3][j]));
#pragma unroll
      for (int d = 1; d < 16; d <<= 1) m = fmaxf(m, __shfl_xor(m, d, 64));
      int r = wr * 64 + mt * 16 + (lane >> 4) * 4 + j;
      if ((lane & 15) == 0) redmax[wc * 128 + r] = m;
    }
  }
  __syncthreads();
#pragma unroll
  for (int mt = 0; mt < 4; mt++) {
#pragma unroll
    for (int j = 0; j < 4; j++) {
      int r = wr * 64 + mt * 16 + (lane >> 4) * 4 + j;
      float M = fmaxf(redmax[r], redmax[128 + r]);
      float sm = 0.f;
#pragma unroll
      for (int nt = 0; nt < 4; nt++) {
        float p = exp2f((s[mt][nt][j] - M) * cexp);
        s[mt][nt][j] = p;
        sm += p;
      }
#pragma unroll
      for (int d = 1; d < 16; d <<= 1) sm += __shfl_xor(sm, d, 64);
      if ((lane & 15) == 0) redsum[wc * 128 + r] = sm;
    }
  }
  __syncthreads();
#pragma unroll
  for (int mt = 0; mt < 4; mt++) {
#pragma unroll
    for (int j = 0; j < 4; j++) {
      int r = wr * 64 + mt * 16 + (lane >> 4) * 4 + j;
      float inv = 1.0f / (redsum[r] + redsum[128 + r]);
#pragma unroll
      for (int nt = 0; nt < 4; nt++) {
        int c = wc * 64 + nt * 16 + (lane & 15);
        attb[r * 136 + c] = f2bf(s[mt][nt][j] * inv);
      }
    }
  }

  // ---- Phase 2: agg = att @ feat, register-prefetch double buffer ----
  const int pl = tid >> 3;
  const int pkc = tid & 7;
  auto loadChunk = [&](uint4 (&r)[4], int ch) {
#pragma unroll
    for (int i = 0; i < 4; i++) {
      int l = i * 32 + pl;
      r[i] = *(const uint4*)(topkb + ((long)g * 128 + l) * 2048 + ch * 64 + pkc * 8);
    }
  };
  auto writeChunk = [&](const uint4 (&r)[4]) {
#pragma unroll
    for (int i = 0; i < 4; i++) {
      int l = i * 32 + pl;
      unsigned short v[8];
      v[0] = (unsigned short)(r[i].x & 0xffff); v[1] = (unsigned short)(r[i].x >> 16);
      v[2] = (unsigned short)(r[i].y & 0xffff); v[3] = (unsigned short)(r[i].y >> 16);
      v[4] = (unsigned short)(r[i].z & 0xffff); v[5] = (unsigned short)(r[i].z >> 16);
      v[6] = (unsigned short)(r[i].w & 0xffff); v[7] = (unsigned short)(r[i].w >> 16);
      int lx = l ^ (pkc << 3);
#pragma unroll
      for (int j = 0; j < 8; j++) featT[(pkc * 8 + j) * 128 + lx] = v[j];
    }
  };
  auto computeChunk = [&](int ch) {
    f32x4 c[2][4] = {};
#pragma unroll
    for (int kb = 0; kb < 4; kb++) {
      short8 af2[2], bf2v[4];
#pragma unroll
      for (int mt = 0; mt < 2; mt++) {
        int r = wave * 32 + mt * 16 + (lane & 15);
        af2[mt] = *(const short8*)&attb[r * 136 + kb * 32 + (lane >> 4) * 8];
      }
#pragma unroll
      for (int nt = 0; nt < 4; nt++) {
        int cc = nt * 16 + (lane & 15);
        int l0 = (kb * 32 + (lane >> 4) * 8) ^ (((cc >> 3) & 7) << 3);
        bf2v[nt] = *(const short8*)&featT[cc * 128 + l0];
      }
#pragma unroll
      for (int mt = 0; mt < 2; mt++)
#pragma unroll
        for (int nt = 0; nt < 4; nt++)
          c[mt][nt] = __builtin_amdgcn_mfma_f32_16x16x32_bf16(af2[mt], bf2v[nt], c[mt][nt], 0, 0, 0);
    }
#pragma unroll
    for (int mt = 0; mt < 2; mt++)
#pragma unroll
      for (int nt = 0; nt < 4; nt++)
#pragma unroll
        for (int j = 0; j < 4; j++) {
          long row = (long)g * 128 + wave * 32 + mt * 16 + (lane >> 4) * 4 + j;
          int col = ch * 64 + nt * 16 + (lane & 15);
          agg[row * 2048 + col] = f2bf(c[mt][nt][j]);
        }
  };

  uint4 rA[4], rB[4];
  loadChunk(rA, 0);
  for (int ch = 0; ch < 32; ch += 2) {
    __syncthreads();
    writeChunk(rA);
    loadChunk(rB, ch + 1);
    __syncthreads();
    computeChunk(ch);
    __syncthreads();
    writeChunk(rB);
    if (ch + 2 < 32) loadChunk(rA, ch + 2);
    __syncthreads();
    computeChunk(ch + 1);
  }
}

// ---------------- pe = protos @ wi2^T  [20,5,256] ---------------------------
__global__ __launch_bounds__(256) void k_pe(const float* __restrict__ protos,
                                            const float* __restrict__ wi2,
                                            float* __restrict__ pe) {
  int n = blockIdx.x, oc = blockIdx.y, tid = threadIdx.x;
  if (tid < 160) {
    int p = tid >> 5, o = oc * 32 + (tid & 31);
    const float* pr = protos + ((long)n * 5 + p) * 2048;
    const float* wr = wi2 + (long)o * 2048;
    float acc = 0.f;
    for (int cidx = 0; cidx < 2048; cidx += 4) {
      float4 a = *(const float4*)(pr + cidx);
      float4 b = *(const float4*)(wr + cidx);
      acc += a.x * b.x + a.y * b.y + a.z * b.z + a.w * b.w;
    }
    pe[((long)n * 5 + p) * 256 + o] = acc;
  }
}

// ---------------- q[n,p,c] = sum_o pe[n,p,o] * wi1[o,c]  (f32) --------------
__global__ __launch_bounds__(256) void k_q(const float* __restrict__ pe,
                                           const float* __restrict__ wi1,
                                           float* __restrict__ q) {
  __shared__ float pel[1280];
  int n = blockIdx.x, cb = blockIdx.y, tid = threadIdx.x;
  for (int i = tid; i < 1280; i += 256) pel[i] = pe[(long)n * 1280 + i];
  __syncthreads();
  int c = cb * 256 + tid;
  float a[5] = {0.f, 0.f, 0.f, 0.f, 0.f};
  for (int o = 0; o < 256; o++) {
    float w = wi1[(long)o * 2048 + c];
#pragma unroll
    for (int p = 0; p < 5; p++) a[p] += pel[p * 256 + o] * w;
  }
#pragma unroll
  for (int p = 0; p < 5; p++) q[((long)n * 5 + p) * 2048 + c] = a[p];
}

// ------- lg partial: lgp[cb][n,p,m] (R5 2-chunk) ---------------------------
__global__ __launch_bounds__(256) void k_lg(const float* __restrict__ q,
                                            const unsigned short* __restrict__ feats,
                                            float* __restrict__ lgp) {
  __shared__ float ql[5 * 1024];
  int n = blockIdx.x, mc = blockIdx.y, cb = blockIdx.z, tid = threadIdx.x;
  const float4* qs = (const float4*)(q + (long)n * 5 * 2048);
  for (int i = tid; i < 1280; i += 256) {
    int p = i >> 8, r = i & 255;
    ((float4*)ql)[i] = qs[p * 512 + cb * 256 + r];
  }
  __syncthreads();
  int m = mc * 256 + tid;
  const unsigned short* fr = feats + ((long)n * 2048 + m) * 2048 + cb * 1024;
  float a[5] = {0.f, 0.f, 0.f, 0.f, 0.f};
  for (int c = 0; c < 1024; c += 8) {
    uint4 w = *(const uint4*)(fr + c);
    float f[8];
    f[0] = bf2f((unsigned short)(w.x & 0xffff)); f[1] = bf2f((unsigned short)(w.x >> 16));
    f[2] = bf2f((unsigned short)(w.y & 0xffff)); f[3] = bf2f((unsigned short)(w.y >> 16));
    f[4] = bf2f((unsigned short)(w.z & 0xffff)); f[5] = bf2f((unsigned short)(w.z >> 16));
    f[6] = bf2f((unsigned short)(w.w & 0xffff)); f[7] = bf2f((unsigned short)(w.w >> 16));
#pragma unroll
    for (int j = 0; j < 8; j++) {
      float fv = f[j];
#pragma unroll
      for (int p = 0; p < 5; p++) a[p] += fv * ql[p * 1024 + c + j];
    }
  }
#pragma unroll
  for (int p = 0; p < 5; p++)
    lgp[((long)cb * 100 + n * 5 + p) * 2048 + m] = a[p] * 0.0625f;
}

// ---------------- softmax over m (2048) per (n,p), 2 partials ---------------
__global__ __launch_bounds__(256) void k_sm(const float* __restrict__ lgp,
                                            float* __restrict__ att2) {
  __shared__ float red[4], red2[4];
  int b = blockIdx.x, tid = threadIdx.x;
  const float* s0 = lgp + (long)b * 2048;
  const float* s1 = lgp + (long)100 * 2048 + (long)b * 2048;
  float v[8];
  float mx = -1e30f;
#pragma unroll
  for (int i = 0; i < 8; i++) {
    v[i] = s0[i * 256 + tid] + s1[i * 256 + tid];
    mx = fmaxf(mx, v[i]);
  }
#pragma unroll
  for (int d = 1; d < 64; d <<= 1) mx = fmaxf(mx, __shfl_xor(mx, d, 64));
  if ((tid & 63) == 0) red[tid >> 6] = mx;
  __syncthreads();
  mx = fmaxf(fmaxf(red[0], red[1]), fmaxf(red[2], red[3]));
  float sm = 0.f;
#pragma unroll
  for (int i = 0; i < 8; i++) { v[i] = exp2f((v[i] - mx) * 1.44269504088896f); sm += v[i]; }
#pragma unroll
  for (int d = 1; d < 64; d <<= 1) sm += __shfl_xor(sm, d, 64);
  if ((tid & 63) == 0) red2[tid >> 6] = sm;
  __syncthreads();
  float inv = 1.0f / (red2[0] + red2[1] + red2[2] + red2[3]);
  float* dst = att2 + (long)b * 2048;
#pragma unroll
  for (int i = 0; i < 8; i++) dst[i * 256 + tid] = v[i] * inv;
}

// ---------------- un_protos partials: att2 @ fa (8 m-chunks, 8B loads) ------
__global__ __launch_bounds__(256) void k_out_part(const float* __restrict__ att2,
                                                  const unsigned short* __restrict__ feats,
                                                  float* __restrict__ partial) {
  __shared__ float a2[5 * 256];
  int n = blockIdx.x, cb = blockIdx.y, ms = blockIdx.z;
  int tid = threadIdx.x;
  const float* src = att2 + (long)n * 5 * 2048 + ms * 256;
  for (int i = tid; i < 320; i += 256) {
    int p = i >> 6, r = i & 63;
    ((float4*)a2)[i] = *(const float4*)(src + p * 2048 + r * 4);
  }
  __syncthreads();
  int c0 = cb * 1024 + tid * 4;
  const unsigned short* fp = feats + ((long)n * 2048 + ms * 256) * 2048 + c0;
  float acc[5][4] = {};
  for (int m = 0; m < 256; m++) {
    uint2 w = *(const uint2*)(fp + (long)m * 2048);
    float f0 = bf2f((unsigned short)(w.x & 0xffff));
    float f1 = bf2f((unsigned short)(w.x >> 16));
    float f2 = bf2f((unsigned short)(w.y & 0xffff));
    float f3 = bf2f((unsigned short)(w.y >> 16));
#pragma unroll
    for (int p = 0; p < 5; p++) {
      float a = a2[p * 256 + m];
      acc[p][0] += a * f0; acc[p][1] += a * f1; acc[p][2] += a * f2; acc[p][3] += a * f3;
    }
  }
  float* pp = partial + ((long)ms * 100 + (long)n * 5) * 2048;
#pragma unroll
  for (int p = 0; p < 5; p++) {
    float4 o; o.x = acc[p][0]; o.y = acc[p][1]; o.z = acc[p][2]; o.w = acc[p][3];
    *(float4*)(pp + p * 2048 + c0) = o;
  }
}

__global__ __launch_bounds__(256) void k_out_red(const float* __restrict__ partial,
                                                 float* __restrict__ outp) {
  int i = blockIdx.x * 256 + threadIdx.x;  // f32x4 idx < 51200
  const f32x4* P = (const f32x4*)partial;
  f32x4 s = P[i];
#pragma unroll
  for (int j = 1; j < 8; j++) s += P[(long)j * 51200 + i];
  ((f32x4*)outp)[i] = s;
}

extern "C" void kernel_launch(void* const* d_in, const int* in_sizes, int n_in,
                              void* d_out, int out_size, void* d_ws, size_t ws_size,
                              hipStream_t stream) {
  const float* topk = (const float*)d_in[0];
  const float* protos = (const float*)d_in[1];
  const float* w1 = (const float*)d_in[2];
  const float* wt = (const float*)d_in[3];
  const float* wi1 = (const float*)d_in[4];
  const float* wi2 = (const float*)d_in[5];
  float* outp = (float*)d_out;

  char* ws = (char*)d_ws;
  size_t off = 0;
  auto alloc = [&](size_t bytes) -> void* {
    void* p = ws + off;
    off += (bytes + 255) & ~(size_t)255;
    return p;
  };
  unsigned short* w1b = (unsigned short*)alloc((size_t)256 * 2048 * 2);
  unsigned short* wtb = (unsigned short*)alloc((size_t)2048 * 2048 * 2);
  unsigned short* topkb = (unsigned short*)alloc((size_t)40960 * 2048 * 2);  // aliased by feats
  unsigned short* fe = (unsigned short*)alloc((size_t)40960 * 256 * 2);
  unsigned short* agg = (unsigned short*)alloc((size_t)40960 * 2048 * 2);
  float* pe = (float*)alloc((size_t)20 * 5 * 256 * 4);
  float* q = (float*)alloc((size_t)20 * 5 * 2048 * 4);
  float* lgp = (float*)alloc((size_t)2 * 100 * 2048 * 4);
  float* att2 = (float*)alloc((size_t)20 * 5 * 2048 * 4);
  float* partial = (float*)alloc((size_t)8 * 100 * 2048 * 4);
  unsigned short* feats = topkb;  // topkb dead after attn

  k_cvt_bf16<<<512, 256, 0, stream>>>(w1, w1b, 131072);
  k_cvt_bf16<<<4096, 256, 0, stream>>>(wt, wtb, 1048576);
  k_cvt_bf16<<<81920, 256, 0, stream>>>(topk, topkb, 20971520);

  // fe = topkb @ W1^T
  k_gemm_bt<false><<<dim3(2, 320), 256, 0, stream>>>(topkb, w1b, fe, nullptr, 256);
  // inner attention -> agg  (register-prefetch phase 2)
  k_attn_inner<<<320, 256, 0, stream>>>(fe, topkb, agg);
  // feats = topkb + relu(agg @ Wt^T)   (R5-proven 8-phase; in-place bf16 resid)
  k_gemm256_8p<true><<<dim3(8, 160), 512, 0, stream>>>(agg, wtb, feats, topkb, 2048);
  // inter attention (fae eliminated: q = pe @ wi1)
  k_pe<<<dim3(20, 8), 256, 0, stream>>>(protos, wi2, pe);
  k_q<<<dim3(20, 8), 256, 0, stream>>>(pe, wi1, q);
  k_lg<<<dim3(20, 8, 2), 256, 0, stream>>>(q, feats, lgp);
  k_sm<<<100, 256, 0, stream>>>(lgp, att2);
  // output
  k_out_part<<<dim3(20, 2, 8), 256, 0, stream>>>(att2, feats, partial);
  k_out_red<<<200, 256, 0, stream>>>(partial, outp);
}